// Round 2
// baseline (4663.485 us; speedup 1.0000x reference)
//
#include <hip/hip_runtime.h>
#include <hip/hip_bf16.h>

typedef unsigned short u16;
typedef unsigned int u32;

#define NN 8192
#define MDIM 512
#define PXC 2560
#define MAXD 48
#define LVL_BLOCKS 512

// ---------------- workspace layout (bytes) ----------------
static constexpr size_t SZ_PX  = (size_t)(NN + 1) * PXC * 2;   // bf16, row NN = zero sentinel
static constexpr size_t SZ_ACC = (size_t)(NN + 1) * MDIM * 4;  // f32
static constexpr size_t SZ_G   = (size_t)NN * 2048 * 4;        // f32 gate scratch (both passes)
static constexpr size_t SZ_WT  = (size_t)5120 * 512 * 2;       // bf16 transposed weights

static constexpr size_t OFF_PX    = 0;
static constexpr size_t OFF_QX    = OFF_PX + SZ_PX;
static constexpr size_t OFF_ACCH  = OFF_QX + SZ_PX;            // CS acc_h; chain reuses as ZB
static constexpr size_t OFF_ACCF  = OFF_ACCH + SZ_ACC;
static constexpr size_t OFF_ACCZ  = OFF_ACCF + SZ_ACC;
static constexpr size_t OFF_H     = OFF_ACCZ + SZ_ACC;         // CS: Hcs ; chain: h_all
static constexpr size_t OFF_C     = OFF_H + SZ_ACC;            // CS: Ccs ; chain: c_all
static constexpr size_t OFF_G     = OFF_C + SZ_ACC;            // also transient home of normalized inputs/weights
static constexpr size_t OFF_WT    = OFF_G + SZ_G;
static constexpr size_t OFF_DEPTH = OFF_WT + SZ_WT;
static constexpr size_t OFF_ORDER = OFF_DEPTH + (size_t)NN * 4;
static constexpr size_t OFF_MISC  = OFF_ORDER + (size_t)NN * 4; // counts[64]+cursor[64]+fcnt+pcnt
static constexpr size_t OFF_LVL   = OFF_MISC + 1024;            // lvlstart[65]
static constexpr size_t OFF_NB    = OFF_LVL + 512;              // normalized biases, bf16, 10240 elems
static constexpr size_t OFF_PN    = OFF_NB + 20480;             // normalized parent, int32[NN]
static constexpr size_t OFF_PMAX  = OFF_PN + (size_t)NN * 4;    // f32 64*512
static constexpr size_t WS_TOTAL  = OFF_PMAX + (size_t)64 * 512 * 4;

// transient normalized-tensor offsets inside G region (elements, bf16)
#define NG_IN    0
#define NG_CSWX  4194304
#define NG_CHWX  5505024
#define NG_CSWIO 6815744
#define NG_CSWFZ 7340032
#define NG_CSWUM 7864320
#define NG_CHWH  8126464
#define NG_CHWUM 9175040

// normalized bias offsets (elements, bf16) inside NB
#define NB_CSBX  0
#define NB_CSBIO 2560
#define NB_CSBFZ 3584
#define NB_CSBUM 4608
#define NB_CHBX  5120
#define NB_CHBH  7680
#define NB_CHBUM 9728

// WT sub-offsets (elements)
#define WT_CIO 0
#define WT_CUM (1024 * 512)
#define WT_CFZ (1536 * 512)
#define WT_HH  (2560 * 512)
#define WT_HUM (4608 * 512)

// ---------------- helpers ----------------
__device__ __forceinline__ float bfu(u16 u) { return __uint_as_float(((u32)u) << 16); }
__device__ __forceinline__ u16 f2bf(float f) {
    u32 u = __float_as_uint(f);
    u += 0x7fffu + ((u >> 16) & 1u);
    return (u16)(u >> 16);
}
// clamped activations: no inf can ever be produced
__device__ __forceinline__ float sigf(float x) {
    x = fminf(fmaxf(x, -30.f), 30.f);
    return 1.f / (1.f + __expf(-x));
}
__device__ __forceinline__ float tanhq(float x) {
    x = fminf(fmaxf(x, -15.f), 15.f);
    return 1.f - 2.f / (__expf(2.f * x) + 1.f);
}

// dot of 512-float LDS row with bf16 weight column (WT4 interleaved layout):
// WT4 element offset for (k, col) = (k&~3)*NC + col*4 + (k&3)
__device__ __forceinline__ float dot512(const float* in_s, const u16* WT, int wcol, int NC) {
    float acc = 0.f;
    const u16* wp = WT + (size_t)wcol * 4;
#pragma unroll 4
    for (int k0 = 0; k0 < 512; k0 += 4) {
        uint2 wv = *(const uint2*)(wp + (size_t)k0 * NC);
        float4 iv = *(const float4*)&in_s[k0];
        acc += iv.x * __uint_as_float((wv.x & 0xffffu) << 16)
             + iv.y * __uint_as_float(wv.x & 0xffff0000u)
             + iv.z * __uint_as_float((wv.y & 0xffffu) << 16)
             + iv.w * __uint_as_float(wv.y & 0xffff0000u);
    }
    return acc;
}

// ---------------- dtype detection + normalization ----------------
// f32-vs-bf16: for bf16 data, low-u16 exponent field of each u32 word clusters
// in [0x70,0x8F] (>95%); for f32 data those bits are mantissa (~12% hit).
__global__ void k_detect(const u32* __restrict__ fin, const u32* __restrict__ pin,
                         int* __restrict__ fcnt, int* __restrict__ pcnt) {
    int i = blockIdx.x * 256 + threadIdx.x; // 4096 threads
    if (i < 4096) {
        u32 w = fin[i];
        int e = (w >> 7) & 0xFF;
        if (w != 0u && e >= 0x70 && e <= 0x8F) atomicAdd(fcnt, 1);
    }
    if (i >= 1 && i < 4096) { // odd word indices 1..8191
        if (pin[2 * i - 1] != 0u) atomicAdd(pcnt, 1);
    }
}

__global__ void k_pnorm(const u32* __restrict__ pin, const int* __restrict__ pcnt,
                        int* __restrict__ pnorm) {
    int i = blockIdx.x * 256 + threadIdx.x;
    if (i >= NN) return;
    bool is64 = (*pcnt < 100);
    pnorm[i] = (int)(is64 ? pin[2 * i] : pin[i]);
}

__global__ void k_normf(const void* __restrict__ src, u16* __restrict__ dst, int count,
                        const int* __restrict__ fcnt) {
    bool isbf = (*fcnt > 2048);
    for (int i = blockIdx.x * 256 + threadIdx.x; i < count; i += gridDim.x * 256) {
        dst[i] = isbf ? ((const u16*)src)[i] : f2bf(((const float*)src)[i]);
    }
}

// ---------------- setup kernels ----------------
__global__ void k_depth(const int* __restrict__ parent, int* __restrict__ depth) {
    int i = blockIdx.x * 256 + threadIdx.x;
    if (i >= NN) return;
    int d = 0, p = parent[i];
    while (p != NN && p >= 0 && p < NN && d < 9000) { d++; p = parent[p]; }
    depth[i] = d;
}

__global__ void k_hist(const int* __restrict__ depth, int* __restrict__ counts) {
    int i = blockIdx.x * 256 + threadIdx.x;
    if (i >= NN) return;
    int d = depth[i]; if (d > 63) d = 63;
    atomicAdd(&counts[d], 1);
}

__global__ void k_scan(const int* __restrict__ counts, int* __restrict__ lvl) {
    if (threadIdx.x == 0) {
        int s = 0;
        lvl[0] = 0;
        for (int d = 0; d < 64; ++d) { s += counts[d]; lvl[d + 1] = s; }
    }
}

__global__ void k_scatter(const int* __restrict__ depth, const int* __restrict__ lvl,
                          int* __restrict__ cursor, int* __restrict__ order) {
    int i = blockIdx.x * 256 + threadIdx.x;
    if (i >= NN) return;
    int d = depth[i]; if (d > 63) d = 63;
    int pos = atomicAdd(&cursor[d], 1);
    order[lvl[d] + pos] = i;
}

// transpose (NC x 512) row-major -> WT4 interleaved
__global__ void k_transpose(const u16* __restrict__ src, u16* __restrict__ dst, int NC) {
    int total = NC * 512;
    for (int e = blockIdx.x * blockDim.x + threadIdx.x; e < total; e += gridDim.x * blockDim.x) {
        int col = e >> 9, k = e & 511;
        dst[(size_t)(k & ~3) * NC + col * 4 + (k & 3)] = src[e];
    }
}

// ---------------- MFMA precompute: C(8192x2560,bf16) = A(8192x512) @ W(2560x512)^T + b ----------------
typedef __attribute__((ext_vector_type(8))) short bf16x8;
typedef __attribute__((ext_vector_type(4))) float f32x4;

__global__ __launch_bounds__(256) void k_gemm_in(const u16* __restrict__ A, const u16* __restrict__ W,
                                                 const u16* __restrict__ bias, u16* __restrict__ C) {
    int wv = threadIdx.x >> 6;
    int L = threadIdx.x & 63;
    int r = L & 15, q = L >> 4;
    int m0 = blockIdx.y * 16;
    int n0 = blockIdx.x * 64 + wv * 16;
    const u16* ap = A + (size_t)(m0 + r) * 512 + q * 8;
    const u16* bp = W + (size_t)(n0 + r) * 512 + q * 8;
    f32x4 acc = {0.f, 0.f, 0.f, 0.f};
#pragma unroll
    for (int k0 = 0; k0 < 512; k0 += 32) {
        bf16x8 a = *(const bf16x8*)(ap + k0);
        bf16x8 b = *(const bf16x8*)(bp + k0);
        acc = __builtin_amdgcn_mfma_f32_16x16x32_bf16(a, b, acc, 0, 0, 0);
    }
    float bv = bfu(bias[n0 + r]);
    size_t base = (size_t)(m0 + q * 4) * PXC + n0 + r;
#pragma unroll
    for (int i = 0; i < 4; ++i) C[base + (size_t)i * PXC] = f2bf(acc[i] + bv);
}

// ---------------- child-sum level kernels ----------------
__global__ __launch_bounds__(256) void cs_k1(const int* __restrict__ order, const int* __restrict__ lvl, int d,
                                             const float* __restrict__ acc_h, const float* __restrict__ acc_zc,
                                             const u16* __restrict__ WT_io, const u16* __restrict__ WT_um,
                                             const u16* __restrict__ bio, const u16* __restrict__ bum,
                                             float* __restrict__ G) {
    __shared__ __align__(16) float in_s[512];
    int start = lvl[d], cnt = lvl[d + 1] - start;
    int t = threadIdx.x;
    for (int w = blockIdx.x; w < cnt * 6; w += gridDim.x) {
        int wi = w / 6, chunk = w - wi * 6;
        int n = order[start + wi];
        const float* row = (chunk < 4) ? (acc_h + (size_t)n * 512) : (acc_zc + (size_t)n * 512);
        __syncthreads();
        in_s[t] = row[t]; in_s[t + 256] = row[t + 256];
        __syncthreads();
        int col = chunk * 256 + t; // 0..1535
        float v;
        if (col < 1024) v = dot512(in_s, WT_io, col, 1024) + bfu(bio[col]);
        else            v = dot512(in_s, WT_um, col - 1024, 512) + bfu(bum[col - 1024]);
        G[(size_t)n * 2048 + col] = v;
    }
}

__global__ __launch_bounds__(256) void cs_k1b(const int* __restrict__ order, const int* __restrict__ lvl, int d,
                                              const int* __restrict__ parent, const u16* __restrict__ px,
                                              const float* __restrict__ G, const float* __restrict__ acc_fc,
                                              float* __restrict__ Ccs, float* __restrict__ Hcs,
                                              float* __restrict__ acc_h, void* __restrict__ outv,
                                              const int* __restrict__ fcnt) {
    int start = lvl[d], cnt = lvl[d + 1] - start;
    int total = cnt * 512;
    bool isbf = (*fcnt > 2048);
    for (int e = blockIdx.x * 256 + threadIdx.x; e < total; e += gridDim.x * 256) {
        int r = e >> 9, j = e & 511;
        int n = order[start + r];
        size_t pxb = (size_t)n * PXC, gb = (size_t)n * 2048, nb = (size_t)n * 512;
        float ig = sigf(bfu(px[pxb + j]) + G[gb + j]);
        float og = sigf(bfu(px[pxb + 1024 + j]) + G[gb + 512 + j]);
        float u  = tanhq(bfu(px[pxb + 2048 + j]) + G[gb + 1024 + j]);
        float c  = ig * u + acc_fc[nb + j];
        float h  = og * tanhq(c);
        Ccs[nb + j] = c; Hcs[nb + j] = h;
        atomicAdd(&acc_h[(size_t)parent[n] * 512 + j], h);
        if (n == 0) {
            if (isbf) ((u16*)outv)[j] = f2bf(h);
            else      ((float*)outv)[j] = h;
        }
    }
}

__global__ __launch_bounds__(256) void cs_k2(const int* __restrict__ order, const int* __restrict__ lvl, int d,
                                             const int* __restrict__ parent, const u16* __restrict__ px,
                                             const u16* __restrict__ WT_fz, const u16* __restrict__ bfz,
                                             const float* __restrict__ Hcs, const float* __restrict__ Ccs,
                                             float* __restrict__ acc_fc, float* __restrict__ acc_zc) {
    __shared__ __align__(16) float in_s[512];
    int start = lvl[d], cnt = lvl[d + 1] - start;
    int t = threadIdx.x;
    for (int w = blockIdx.x; w < cnt * 4; w += gridDim.x) {
        int n = order[start + (w >> 2)];
        int chunk = w & 3;
        size_t nb = (size_t)n * 512;
        __syncthreads();
        in_s[t] = Hcs[nb + t]; in_s[t + 256] = Hcs[nb + 256 + t];
        __syncthreads();
        int col = chunk * 256 + t; // 0..1023
        float fz = dot512(in_s, WT_fz, col, 1024) + bfu(bfz[col]);
        int p = parent[n];
        size_t pb = (size_t)p * PXC;
        if (col < 512) {
            float f = sigf(bfu(px[pb + 512 + col]) + fz);
            atomicAdd(&acc_fc[(size_t)p * 512 + col], f * Ccs[nb + col]);
        } else {
            int j = col - 512;
            float z = sigf(bfu(px[pb + 1536 + j]) + fz);
            atomicAdd(&acc_zc[(size_t)p * 512 + j], z * tanhq(Ccs[nb + j]));
        }
    }
}

// ---------------- chain level kernels ----------------
__global__ __launch_bounds__(256) void ch_k1(const int* __restrict__ order, const int* __restrict__ lvl, int d,
                                             const int* __restrict__ parent, const float* __restrict__ Hall,
                                             const u16* __restrict__ WT_hh, const u16* __restrict__ bh,
                                             float* __restrict__ G) {
    __shared__ __align__(16) float in_s[512];
    int start = lvl[d], cnt = lvl[d + 1] - start;
    int t = threadIdx.x;
    for (int w = blockIdx.x; w < cnt * 8; w += gridDim.x) {
        int n = order[start + (w >> 3)];
        int chunk = w & 7;
        size_t pb = (size_t)parent[n] * 512;
        __syncthreads();
        in_s[t] = Hall[pb + t]; in_s[t + 256] = Hall[pb + 256 + t];
        __syncthreads();
        int col = chunk * 256 + t; // 0..2047
        G[(size_t)n * 2048 + col] = dot512(in_s, WT_hh, col, 2048) + bfu(bh[col]);
    }
}

__global__ __launch_bounds__(256) void ch_k1b(const int* __restrict__ order, const int* __restrict__ lvl, int d,
                                              const int* __restrict__ parent, const u16* __restrict__ qx,
                                              const float* __restrict__ G, const float* __restrict__ Call,
                                              float* __restrict__ ZB) {
    int start = lvl[d], cnt = lvl[d + 1] - start;
    int total = cnt * 512;
    for (int e = blockIdx.x * 256 + threadIdx.x; e < total; e += gridDim.x * 256) {
        int r = e >> 9, j = e & 511;
        int n = order[start + r];
        float zg = sigf(bfu(qx[(size_t)n * PXC + 1536 + j]) + G[(size_t)n * 2048 + 1536 + j]);
        ZB[(size_t)n * 512 + j] = zg * tanhq(Call[(size_t)parent[n] * 512 + j]);
    }
}

__global__ __launch_bounds__(256) void ch_k2(const int* __restrict__ order, const int* __restrict__ lvl, int d,
                                             const int* __restrict__ parent, const u16* __restrict__ qx,
                                             const u16* __restrict__ WT_um, const u16* __restrict__ bum,
                                             const float* __restrict__ ZB, const float* __restrict__ G,
                                             float* __restrict__ Call, float* __restrict__ Hall) {
    __shared__ __align__(16) float in_s[512];
    int start = lvl[d], cnt = lvl[d + 1] - start;
    int t = threadIdx.x;
    for (int w = blockIdx.x; w < cnt * 2; w += gridDim.x) {
        int n = order[start + (w >> 1)];
        int chunk = w & 1;
        size_t nb = (size_t)n * 512;
        __syncthreads();
        in_s[t] = ZB[nb + t]; in_s[t + 256] = ZB[nb + 256 + t];
        __syncthreads();
        int col = chunk * 256 + t; // 0..511
        float up = dot512(in_s, WT_um, col, 512) + bfu(bum[col]);
        size_t qb = (size_t)n * PXC, gb = (size_t)n * 2048;
        float u  = tanhq(bfu(qx[qb + 2048 + col]) + up);
        float ig = sigf(bfu(qx[qb + col]) + G[gb + col]);
        float og = sigf(bfu(qx[qb + 512 + col]) + G[gb + 512 + col]);
        float fg = sigf(bfu(qx[qb + 1024 + col]) + G[gb + 1024 + col]);
        float pc = Call[(size_t)parent[n] * 512 + col];
        float c = ig * u + fg * pc;
        float h = og * tanhq(c);
        Call[nb + col] = c; Hall[nb + col] = h;
    }
}

// ---------------- final max reduce ----------------
__global__ __launch_bounds__(256) void k_maxA(const float* __restrict__ H, float* __restrict__ pmax) {
    int b = blockIdx.x, t = threadIdx.x;
    float m1 = -1e30f, m2 = -1e30f;
    for (int r = b * 128; r < b * 128 + 128; ++r) {
        m1 = fmaxf(m1, H[(size_t)r * 512 + t]);
        m2 = fmaxf(m2, H[(size_t)r * 512 + t + 256]);
    }
    pmax[(size_t)b * 512 + t] = m1; pmax[(size_t)b * 512 + t + 256] = m2;
}

__global__ void k_maxB(const float* __restrict__ pmax, void* __restrict__ outv,
                       const int* __restrict__ fcnt) {
    int j = threadIdx.x; // 512
    float m = -1e30f;
    for (int b = 0; b < 64; ++b) m = fmaxf(m, pmax[(size_t)b * 512 + j]);
    bool isbf = (*fcnt > 2048);
    if (isbf) ((u16*)outv)[512 + j] = f2bf(m);
    else      ((float*)outv)[512 + j] = m;
}

__global__ void k_wsfail(u16* out) {
    int i = blockIdx.x * 256 + threadIdx.x;
    if (i < 1024) out[i] = f2bf(12345.f); // distinctive marker: ws_size too small
}

// ---------------- launch ----------------
extern "C" void kernel_launch(void* const* d_in, const int* in_sizes, int n_in,
                              void* d_out, int out_size, void* d_ws, size_t ws_size,
                              hipStream_t stream) {
    char* base = (char*)d_ws;
    u16* px = (u16*)(base + OFF_PX);
    u16* qx = (u16*)(base + OFF_QX);
    float* acc_h = (float*)(base + OFF_ACCH);
    float* acc_fc = (float*)(base + OFF_ACCF);
    float* acc_zc = (float*)(base + OFF_ACCZ);
    float* Harr = (float*)(base + OFF_H);
    float* Carr = (float*)(base + OFF_C);
    float* G = (float*)(base + OFF_G);
    u16* NG = (u16*)(base + OFF_G);       // transient normalized tensors overlay G
    u16* WT = (u16*)(base + OFF_WT);
    int* depth = (int*)(base + OFF_DEPTH);
    int* order = (int*)(base + OFF_ORDER);
    int* counts = (int*)(base + OFF_MISC);
    int* cursor = counts + 64;
    int* fcnt = counts + 128;
    int* pcnt = counts + 129;
    int* lvl = (int*)(base + OFF_LVL);
    u16* NB = (u16*)(base + OFF_NB);
    int* pnorm = (int*)(base + OFF_PN);
    float* pmax = (float*)(base + OFF_PMAX);

    if (ws_size < WS_TOTAL) { k_wsfail<<<4, 256, 0, stream>>>((u16*)d_out); return; }

    // zero-init (ws may be poisoned/garbage before every call)
    hipMemsetAsync(base + OFF_MISC, 0, 1024, stream);                            // counts/cursor/flags
    hipMemsetAsync(base + OFF_ACCH, 0, 3 * SZ_ACC, stream);                      // acc_h/fc/zc
    hipMemsetAsync(base + OFF_H, 0, 2 * SZ_ACC, stream);                         // Harr/Carr full
    hipMemsetAsync((char*)(px + (size_t)NN * PXC), 0, PXC * 2, stream);          // px sentinel row
    hipMemsetAsync((char*)(qx + (size_t)NN * PXC), 0, PXC * 2, stream);          // qx sentinel row

    // dtype detection + normalization
    k_detect<<<16, 256, 0, stream>>>((const u32*)d_in[0], (const u32*)d_in[1], fcnt, pcnt);
    k_pnorm<<<32, 256, 0, stream>>>((const u32*)d_in[1], pcnt, pnorm);
    k_normf<<<512, 256, 0, stream>>>(d_in[0],  NG + NG_IN,    NN * 512,   fcnt); // inputs
    k_normf<<<256, 256, 0, stream>>>(d_in[2],  NG + NG_CSWX,  2560 * 512, fcnt); // cs_Wx
    k_normf<<<256, 256, 0, stream>>>(d_in[10], NG + NG_CHWX,  2560 * 512, fcnt); // ch_Wx
    k_normf<<<128, 256, 0, stream>>>(d_in[4],  NG + NG_CSWIO, 1024 * 512, fcnt); // cs_Wio
    k_normf<<<128, 256, 0, stream>>>(d_in[6],  NG + NG_CSWFZ, 1024 * 512, fcnt); // cs_Wfz
    k_normf<<<64,  256, 0, stream>>>(d_in[8],  NG + NG_CSWUM, 512 * 512,  fcnt); // cs_Wum
    k_normf<<<128, 256, 0, stream>>>(d_in[12], NG + NG_CHWH,  2048 * 512, fcnt); // ch_Wh
    k_normf<<<64,  256, 0, stream>>>(d_in[14], NG + NG_CHWUM, 512 * 512,  fcnt); // ch_Wum
    k_normf<<<4, 256, 0, stream>>>(d_in[3],  NB + NB_CSBX,  2560, fcnt);
    k_normf<<<4, 256, 0, stream>>>(d_in[5],  NB + NB_CSBIO, 1024, fcnt);
    k_normf<<<4, 256, 0, stream>>>(d_in[7],  NB + NB_CSBFZ, 1024, fcnt);
    k_normf<<<2, 256, 0, stream>>>(d_in[9],  NB + NB_CSBUM, 512,  fcnt);
    k_normf<<<4, 256, 0, stream>>>(d_in[11], NB + NB_CHBX,  2560, fcnt);
    k_normf<<<4, 256, 0, stream>>>(d_in[13], NB + NB_CHBH,  2048, fcnt);
    k_normf<<<2, 256, 0, stream>>>(d_in[15], NB + NB_CHBUM, 512,  fcnt);

    // level schedule
    k_depth<<<32, 256, 0, stream>>>(pnorm, depth);
    k_hist<<<32, 256, 0, stream>>>(depth, counts);
    k_scan<<<1, 64, 0, stream>>>(counts, lvl);
    k_scatter<<<32, 256, 0, stream>>>(depth, lvl, cursor, order);

    // weight transposes (from normalized copies)
    k_transpose<<<256, 256, 0, stream>>>(NG + NG_CSWIO, WT + WT_CIO, 1024);
    k_transpose<<<256, 256, 0, stream>>>(NG + NG_CSWUM, WT + WT_CUM, 512);
    k_transpose<<<256, 256, 0, stream>>>(NG + NG_CSWFZ, WT + WT_CFZ, 1024);
    k_transpose<<<256, 256, 0, stream>>>(NG + NG_CHWH,  WT + WT_HH, 2048);
    k_transpose<<<256, 256, 0, stream>>>(NG + NG_CHWUM, WT + WT_HUM, 512);

    // input projections (MFMA) — must finish before cs levels overwrite G region
    dim3 gg(PXC / 64, NN / 16);
    k_gemm_in<<<gg, 256, 0, stream>>>(NG + NG_IN, NG + NG_CSWX, NB + NB_CSBX, px);
    k_gemm_in<<<gg, 256, 0, stream>>>(NG + NG_IN, NG + NG_CHWX, NB + NB_CHBX, qx);

    // child-sum: deepest level -> root
    for (int d = MAXD - 1; d >= 0; --d) {
        cs_k1<<<LVL_BLOCKS, 256, 0, stream>>>(order, lvl, d, acc_h, acc_zc,
                                              WT + WT_CIO, WT + WT_CUM, NB + NB_CSBIO, NB + NB_CSBUM, G);
        cs_k1b<<<256, 256, 0, stream>>>(order, lvl, d, pnorm, px, G, acc_fc,
                                        Carr, Harr, acc_h, d_out, fcnt);
        cs_k2<<<LVL_BLOCKS, 256, 0, stream>>>(order, lvl, d, pnorm, px,
                                              WT + WT_CFZ, NB + NB_CSBFZ, Harr, Carr, acc_fc, acc_zc);
    }

    // chain: re-zero h_all/c_all (they were used as Hcs/Ccs) incl. sentinel row
    hipMemsetAsync(base + OFF_H, 0, 2 * SZ_ACC, stream);
    for (int d = 0; d < MAXD; ++d) {
        ch_k1<<<LVL_BLOCKS, 256, 0, stream>>>(order, lvl, d, pnorm, Harr,
                                              WT + WT_HH, NB + NB_CHBH, G);
        ch_k1b<<<256, 256, 0, stream>>>(order, lvl, d, pnorm, qx, G, Carr, acc_h /*ZB*/);
        ch_k2<<<LVL_BLOCKS, 256, 0, stream>>>(order, lvl, d, pnorm, qx,
                                              WT + WT_HUM, NB + NB_CHBUM, acc_h /*ZB*/, G, Carr, Harr);
    }

    // brep = max over h_all rows
    k_maxA<<<64, 256, 0, stream>>>(Harr, pmax);
    k_maxB<<<1, 512, 0, stream>>>(pmax, d_out, fcnt);
}

// Round 3
// 3955.922 us; speedup vs baseline: 1.1789x; 1.1789x over previous
//
#include <hip/hip_runtime.h>
#include <hip/hip_bf16.h>

typedef unsigned short u16;
typedef unsigned int u32;

#define NN 8192
#define PXC 2560
#define MAXD 48
#define LVL_WG 120

typedef __attribute__((ext_vector_type(8))) short bf16x8;
typedef __attribute__((ext_vector_type(4))) float f32x4;

// ---------------- workspace layout (bytes) ----------------
static constexpr size_t SZ_PX  = (size_t)(NN + 1) * PXC * 2;   // bf16, row NN zero sentinel
static constexpr size_t SZ_ACC = (size_t)(NN + 1) * 512 * 4;   // f32
static constexpr size_t SZ_HB  = (size_t)(NN + 1) * 512 * 2;   // bf16
static constexpr size_t SZ_G   = (size_t)NN * 1536 * 4;        // f32 chain gate scratch
static constexpr size_t SZ_NW  = (size_t)5242880 * 2;          // bf16 normalized weights

static constexpr size_t OFF_PX    = 0;
static constexpr size_t OFF_QX    = OFF_PX + SZ_PX;
static constexpr size_t OFF_ACCH  = OFF_QX + SZ_PX;
static constexpr size_t OFF_ACCF  = OFF_ACCH + SZ_ACC;
static constexpr size_t OFF_ACCZ  = OFF_ACCF + SZ_ACC;
static constexpr size_t OFF_C     = OFF_ACCZ + SZ_ACC;         // Ccs / c_all, f32
static constexpr size_t OFF_HB    = OFF_C + SZ_ACC;            // Hcs / h_all, bf16
static constexpr size_t OFF_ZB    = OFF_HB + SZ_HB;            // chain z*tanh(pc), bf16
static constexpr size_t OFF_G     = OFF_ZB + SZ_HB;            // chain gates; first 8.4MB = normalized inputs (transient)
static constexpr size_t OFF_NW    = OFF_G + SZ_G;
static constexpr size_t OFF_DEPTH = OFF_NW + SZ_NW;
static constexpr size_t OFF_ORDER = OFF_DEPTH + (size_t)NN * 4;
static constexpr size_t OFF_MISC  = OFF_ORDER + (size_t)NN * 4; // counts[64]+cursor[64]+fcnt+pcnt
static constexpr size_t OFF_LVL   = OFF_MISC + 1024;
static constexpr size_t OFF_NB    = OFF_LVL + 512;              // normalized biases bf16 (10240)
static constexpr size_t OFF_PN    = OFF_NB + 20480;             // parent int32
static constexpr size_t OFF_PMAX  = OFF_PN + (size_t)NN * 4;
static constexpr size_t WS_TOTAL  = OFF_PMAX + (size_t)64 * 512 * 4; // ~229MB (round-2 240MB fit)

// normalized-weight element offsets
#define NW_CSWX  0
#define NW_CHWX  1310720
#define NW_CSWIO 2621440
#define NW_CSWFZ 3145728
#define NW_CSWUM 3670016
#define NW_CHWH  3932160
#define NW_CHWUM 4980736

// normalized bias element offsets
#define NB_CSBX  0
#define NB_CSBIO 2560
#define NB_CSBFZ 3584
#define NB_CSBUM 4608
#define NB_CHBX  5120
#define NB_CHBH  7680
#define NB_CHBUM 9728

// ---------------- helpers ----------------
__device__ __forceinline__ float bfu(u16 u) { return __uint_as_float(((u32)u) << 16); }
__device__ __forceinline__ u16 f2bf(float f) {
    u32 u = __float_as_uint(f);
    u += 0x7fffu + ((u >> 16) & 1u);
    return (u16)(u >> 16);
}
__device__ __forceinline__ float sigf(float x) {
    x = fminf(fmaxf(x, -30.f), 30.f);
    return 1.f / (1.f + __expf(-x));
}
__device__ __forceinline__ float tanhq(float x) {
    x = fminf(fmaxf(x, -15.f), 15.f);
    return 1.f - 2.f / (__expf(2.f * x) + 1.f);
}
// f32x8 -> bf16x8 (round-half-up, 5 VALU per pair)
__device__ __forceinline__ bf16x8 cvt8(const float* p) {
    float4 a = *(const float4*)p;
    float4 b = *(const float4*)(p + 4);
    union { u32 u[4]; bf16x8 v; } r;
    r.u[0] = ((__float_as_uint(a.x) + 0x8000u) >> 16) | ((__float_as_uint(a.y) + 0x8000u) & 0xffff0000u);
    r.u[1] = ((__float_as_uint(a.z) + 0x8000u) >> 16) | ((__float_as_uint(a.w) + 0x8000u) & 0xffff0000u);
    r.u[2] = ((__float_as_uint(b.x) + 0x8000u) >> 16) | ((__float_as_uint(b.y) + 0x8000u) & 0xffff0000u);
    r.u[3] = ((__float_as_uint(b.z) + 0x8000u) >> 16) | ((__float_as_uint(b.w) + 0x8000u) & 0xffff0000u);
    return r.v;
}

// ---------------- dtype detection + normalization ----------------
__global__ void k_detect(const u32* __restrict__ fin, const u32* __restrict__ pin,
                         int* __restrict__ fcnt, int* __restrict__ pcnt) {
    int i = blockIdx.x * 256 + threadIdx.x;
    if (i < 4096) {
        u32 w = fin[i];
        int e = (w >> 7) & 0xFF;
        if (w != 0u && e >= 0x70 && e <= 0x8F) atomicAdd(fcnt, 1);
    }
    if (i >= 1 && i < 4096) {
        if (pin[2 * i - 1] != 0u) atomicAdd(pcnt, 1);
    }
}

__global__ void k_pnorm(const u32* __restrict__ pin, const int* __restrict__ pcnt,
                        int* __restrict__ pnorm) {
    int i = blockIdx.x * 256 + threadIdx.x;
    if (i >= NN) return;
    bool is64 = (*pcnt < 100);
    pnorm[i] = (int)(is64 ? pin[2 * i] : pin[i]);
}

__global__ void k_normf4(const void* __restrict__ src, u16* __restrict__ dst, int count4,
                         const int* __restrict__ fcnt) {
    bool isbf = (*fcnt > 2048);
    int i = blockIdx.x * 256 + threadIdx.x;
    if (i >= count4) return;
    if (isbf) {
        ((ushort4*)dst)[i] = ((const ushort4*)src)[i];
    } else {
        float4 v = ((const float4*)src)[i];
        ushort4 o; o.x = f2bf(v.x); o.y = f2bf(v.y); o.z = f2bf(v.z); o.w = f2bf(v.w);
        ((ushort4*)dst)[i] = o;
    }
}

// ---------------- level schedule ----------------
__global__ void k_depth(const int* __restrict__ parent, int* __restrict__ depth) {
    int i = blockIdx.x * 256 + threadIdx.x;
    if (i >= NN) return;
    int d = 0, p = parent[i];
    while (p != NN && p >= 0 && p < NN && d < 9000) { d++; p = parent[p]; }
    depth[i] = d;
}
__global__ void k_hist(const int* __restrict__ depth, int* __restrict__ counts) {
    int i = blockIdx.x * 256 + threadIdx.x;
    if (i >= NN) return;
    int d = depth[i]; if (d > 63) d = 63;
    atomicAdd(&counts[d], 1);
}
__global__ void k_scan(const int* __restrict__ counts, int* __restrict__ lvl) {
    if (threadIdx.x == 0) {
        int s = 0; lvl[0] = 0;
        for (int d = 0; d < 64; ++d) { s += counts[d]; lvl[d + 1] = s; }
    }
}
__global__ void k_scatter(const int* __restrict__ depth, const int* __restrict__ lvl,
                          int* __restrict__ cursor, int* __restrict__ order) {
    int i = blockIdx.x * 256 + threadIdx.x;
    if (i >= NN) return;
    int d = depth[i]; if (d > 63) d = 63;
    int pos = atomicAdd(&cursor[d], 1);
    order[lvl[d] + pos] = i;
}

// ---------------- input-projection GEMM: C(8192x2560 bf16) = A @ W^T + b ----------------
__global__ __launch_bounds__(256) void k_gemm_in(const u16* __restrict__ A, const u16* __restrict__ W,
                                                 const u16* __restrict__ bias, u16* __restrict__ C) {
    int wv = threadIdx.x >> 6;
    int L = threadIdx.x & 63;
    int r = L & 15, q = L >> 4;
    int m0 = blockIdx.y * 16;
    int n0 = blockIdx.x * 64 + wv * 16;
    const u16* ap = A + (size_t)(m0 + r) * 512 + q * 8;
    const u16* bp = W + (size_t)(n0 + r) * 512 + q * 8;
    f32x4 acc = {0.f, 0.f, 0.f, 0.f};
#pragma unroll
    for (int k0 = 0; k0 < 512; k0 += 32) {
        acc = __builtin_amdgcn_mfma_f32_16x16x32_bf16(*(const bf16x8*)(ap + k0),
                                                      *(const bf16x8*)(bp + k0), acc, 0, 0, 0);
    }
    float bv = bfu(bias[n0 + r]);
    size_t base = (size_t)(m0 + q * 4) * PXC + n0 + r;
#pragma unroll
    for (int i = 0; i < 4; ++i) C[base + (size_t)i * PXC] = f2bf(acc[i] + bv);
}

// ---------------- child-sum fused level kernels ----------------
// step1: [i,o,u] gate GEMMs + gates -> c,h; scatter h into acc_h[parent]; root -> out
__global__ __launch_bounds__(256) void cs_lvl1(
    const int* __restrict__ order, const int* __restrict__ lvl, int d,
    const int* __restrict__ parent,
    float* acc_h /*read A + atomic write*/, const float* __restrict__ acc_zc,
    const float* __restrict__ acc_fc,
    const u16* __restrict__ Wio, const u16* __restrict__ Wum,
    const u16* __restrict__ bio, const u16* __restrict__ bum,
    const u16* __restrict__ px,
    float* __restrict__ Ccs, u16* __restrict__ HB,
    void* __restrict__ outv, const int* __restrict__ fcnt)
{
    int start = lvl[d], cnt = lvl[d + 1] - start;
    if (cnt <= 0) return;
    int ntiles = (cnt + 15) >> 4;
    int W = ntiles * 8;
    int lane = threadIdx.x & 63;
    int r = lane & 15, q = lane >> 4;
    int wave0 = blockIdx.x * (blockDim.x >> 6) + (threadIdx.x >> 6);
    int wstep = gridDim.x * (blockDim.x >> 6);
    bool isbf = (*fcnt > 2048);
    for (int w = wave0; w < W; w += wstep) {
        int tile = w >> 3, jb = w & 7, j0 = jb * 64;
        int tr = tile * 16 + r;
        int rA = (tr < cnt) ? order[start + tr] : NN;
        const float* pah = acc_h + (size_t)rA * 512 + q * 8;
        const float* paz = acc_zc + (size_t)rA * 512 + q * 8;
        const u16 *pbi[4], *pbo[4], *pbu[4];
#pragma unroll
        for (int jt = 0; jt < 4; ++jt) {
            int n0 = j0 + jt * 16 + r;
            pbi[jt] = Wio + (size_t)n0 * 512 + q * 8;
            pbo[jt] = Wio + (size_t)(512 + n0) * 512 + q * 8;
            pbu[jt] = Wum + (size_t)n0 * 512 + q * 8;
        }
        f32x4 ai[4] = {}, ao[4] = {}, au[4] = {};
#pragma unroll 4
        for (int ko = 0; ko < 512; ko += 32) {
            bf16x8 a_h = cvt8(pah + ko);
            bf16x8 a_z = cvt8(paz + ko);
#pragma unroll
            for (int jt = 0; jt < 4; ++jt) {
                ai[jt] = __builtin_amdgcn_mfma_f32_16x16x32_bf16(a_h, *(const bf16x8*)(pbi[jt] + ko), ai[jt], 0, 0, 0);
                ao[jt] = __builtin_amdgcn_mfma_f32_16x16x32_bf16(a_h, *(const bf16x8*)(pbo[jt] + ko), ao[jt], 0, 0, 0);
                au[jt] = __builtin_amdgcn_mfma_f32_16x16x32_bf16(a_z, *(const bf16x8*)(pbu[jt] + ko), au[jt], 0, 0, 0);
            }
        }
#pragma unroll
        for (int i2 = 0; i2 < 4; ++i2) {
            int ti = tile * 16 + q * 4 + i2;
            if (ti >= cnt) continue;
            int ni = order[start + ti];
            int p = parent[ni];
            size_t pxb = (size_t)ni * PXC, nb = (size_t)ni * 512, pb = (size_t)p * 512;
#pragma unroll
            for (int jt = 0; jt < 4; ++jt) {
                int c = j0 + jt * 16 + r;
                float ig = sigf(bfu(px[pxb + c]) + ai[jt][i2] + bfu(bio[c]));
                float og = sigf(bfu(px[pxb + 1024 + c]) + ao[jt][i2] + bfu(bio[512 + c]));
                float uu = tanhq(bfu(px[pxb + 2048 + c]) + au[jt][i2] + bfu(bum[c]));
                float cc = ig * uu + acc_fc[nb + c];
                float h = og * tanhq(cc);
                Ccs[nb + c] = cc;
                HB[nb + c] = f2bf(h);
                atomicAdd(&acc_h[pb + c], h);
                if (ni == 0) {
                    if (isbf) ((u16*)outv)[c] = f2bf(h);
                    else ((float*)outv)[c] = h;
                }
            }
        }
    }
}

// step2: [f,z] GEMMs on h; scatter f*c, z*tanh(c) into parent's accumulators
__global__ __launch_bounds__(256) void cs_lvl2(
    const int* __restrict__ order, const int* __restrict__ lvl, int d,
    const int* __restrict__ parent,
    const u16* __restrict__ HB, const float* __restrict__ Ccs,
    const u16* __restrict__ Wfz, const u16* __restrict__ bfz,
    const u16* __restrict__ px,
    float* __restrict__ acc_fc, float* __restrict__ acc_zc)
{
    int start = lvl[d], cnt = lvl[d + 1] - start;
    if (cnt <= 0) return;
    int ntiles = (cnt + 15) >> 4;
    int W = ntiles * 8;
    int lane = threadIdx.x & 63;
    int r = lane & 15, q = lane >> 4;
    int wave0 = blockIdx.x * (blockDim.x >> 6) + (threadIdx.x >> 6);
    int wstep = gridDim.x * (blockDim.x >> 6);
    for (int w = wave0; w < W; w += wstep) {
        int tile = w >> 3, jb = w & 7, j0 = jb * 64;
        int tr = tile * 16 + r;
        int rA = (tr < cnt) ? order[start + tr] : NN;
        const u16* pa = HB + (size_t)rA * 512 + q * 8;
        const u16 *pbf[4], *pbz[4];
#pragma unroll
        for (int jt = 0; jt < 4; ++jt) {
            int n0 = j0 + jt * 16 + r;
            pbf[jt] = Wfz + (size_t)n0 * 512 + q * 8;
            pbz[jt] = Wfz + (size_t)(512 + n0) * 512 + q * 8;
        }
        f32x4 af[4] = {}, az[4] = {};
#pragma unroll 4
        for (int ko = 0; ko < 512; ko += 32) {
            bf16x8 a = *(const bf16x8*)(pa + ko);
#pragma unroll
            for (int jt = 0; jt < 4; ++jt) {
                af[jt] = __builtin_amdgcn_mfma_f32_16x16x32_bf16(a, *(const bf16x8*)(pbf[jt] + ko), af[jt], 0, 0, 0);
                az[jt] = __builtin_amdgcn_mfma_f32_16x16x32_bf16(a, *(const bf16x8*)(pbz[jt] + ko), az[jt], 0, 0, 0);
            }
        }
#pragma unroll
        for (int i2 = 0; i2 < 4; ++i2) {
            int ti = tile * 16 + q * 4 + i2;
            if (ti >= cnt) continue;
            int ni = order[start + ti];
            int p = parent[ni];
            size_t nb = (size_t)ni * 512, pb = (size_t)p * 512, ppx = (size_t)p * PXC;
#pragma unroll
            for (int jt = 0; jt < 4; ++jt) {
                int c = j0 + jt * 16 + r;
                float cT = Ccs[nb + c];
                float f = sigf(bfu(px[ppx + 512 + c]) + af[jt][i2] + bfu(bfz[c]));
                atomicAdd(&acc_fc[pb + c], f * cT);
                float z = sigf(bfu(px[ppx + 1536 + c]) + az[jt][i2] + bfu(bfz[512 + c]));
                atomicAdd(&acc_zc[pb + c], z * tanhq(cT));
            }
        }
    }
}

// ---------------- chain fused level kernels ----------------
// step1: 4-gate GEMM from parent's h; store i,o,f pre-acts; ZB = sig(z)*tanh(pc)
__global__ __launch_bounds__(256) void ch_lvl1(
    const int* __restrict__ order, const int* __restrict__ lvl, int d,
    const int* __restrict__ parent,
    const u16* __restrict__ HB, const float* __restrict__ Call,
    const u16* __restrict__ Wh, const u16* __restrict__ bh,
    const u16* __restrict__ qx,
    float* __restrict__ G, u16* __restrict__ ZB)
{
    int start = lvl[d], cnt = lvl[d + 1] - start;
    if (cnt <= 0) return;
    int ntiles = (cnt + 15) >> 4;
    int W = ntiles * 8;
    int lane = threadIdx.x & 63;
    int r = lane & 15, q = lane >> 4;
    int wave0 = blockIdx.x * (blockDim.x >> 6) + (threadIdx.x >> 6);
    int wstep = gridDim.x * (blockDim.x >> 6);
    for (int w = wave0; w < W; w += wstep) {
        int tile = w >> 3, jb = w & 7, j0 = jb * 64;
        int tr = tile * 16 + r;
        int nod = (tr < cnt) ? order[start + tr] : -1;
        int rP = (nod < 0) ? NN : parent[nod];
        const u16* pa = HB + (size_t)rP * 512 + q * 8;
        const u16 *pbi[4], *pbo[4], *pbf[4], *pbz[4];
#pragma unroll
        for (int jt = 0; jt < 4; ++jt) {
            int n0 = j0 + jt * 16 + r;
            pbi[jt] = Wh + (size_t)n0 * 512 + q * 8;
            pbo[jt] = Wh + (size_t)(512 + n0) * 512 + q * 8;
            pbf[jt] = Wh + (size_t)(1024 + n0) * 512 + q * 8;
            pbz[jt] = Wh + (size_t)(1536 + n0) * 512 + q * 8;
        }
        f32x4 gi[4] = {}, go[4] = {}, gf[4] = {}, gz[4] = {};
#pragma unroll 2
        for (int ko = 0; ko < 512; ko += 32) {
            bf16x8 a = *(const bf16x8*)(pa + ko);
#pragma unroll
            for (int jt = 0; jt < 4; ++jt) {
                gi[jt] = __builtin_amdgcn_mfma_f32_16x16x32_bf16(a, *(const bf16x8*)(pbi[jt] + ko), gi[jt], 0, 0, 0);
                go[jt] = __builtin_amdgcn_mfma_f32_16x16x32_bf16(a, *(const bf16x8*)(pbo[jt] + ko), go[jt], 0, 0, 0);
                gf[jt] = __builtin_amdgcn_mfma_f32_16x16x32_bf16(a, *(const bf16x8*)(pbf[jt] + ko), gf[jt], 0, 0, 0);
                gz[jt] = __builtin_amdgcn_mfma_f32_16x16x32_bf16(a, *(const bf16x8*)(pbz[jt] + ko), gz[jt], 0, 0, 0);
            }
        }
#pragma unroll
        for (int i2 = 0; i2 < 4; ++i2) {
            int ti = tile * 16 + q * 4 + i2;
            if (ti >= cnt) continue;
            int ni = order[start + ti];
            int p = parent[ni];
            size_t gb = (size_t)ni * 1536, nb = (size_t)ni * 512, pb = (size_t)p * 512;
            size_t qb = (size_t)ni * PXC;
#pragma unroll
            for (int jt = 0; jt < 4; ++jt) {
                int c = j0 + jt * 16 + r;
                G[gb + c]        = gi[jt][i2] + bfu(bh[c]);
                G[gb + 512 + c]  = go[jt][i2] + bfu(bh[512 + c]);
                G[gb + 1024 + c] = gf[jt][i2] + bfu(bh[1024 + c]);
                float zg = sigf(bfu(qx[qb + 1536 + c]) + gz[jt][i2] + bfu(bh[1536 + c]));
                ZB[nb + c] = f2bf(zg * tanhq(Call[pb + c]));
            }
        }
    }
}

// step2: u-GEMM on ZB; gates -> c,h
__global__ __launch_bounds__(256) void ch_lvl2(
    const int* __restrict__ order, const int* __restrict__ lvl, int d,
    const int* __restrict__ parent,
    const u16* __restrict__ ZB, const u16* __restrict__ qx,
    const u16* __restrict__ Wum, const u16* __restrict__ bum,
    const float* __restrict__ G, float* __restrict__ Call, u16* __restrict__ HB)
{
    int start = lvl[d], cnt = lvl[d + 1] - start;
    if (cnt <= 0) return;
    int ntiles = (cnt + 15) >> 4;
    int W = ntiles * 8;
    int lane = threadIdx.x & 63;
    int r = lane & 15, q = lane >> 4;
    int wave0 = blockIdx.x * (blockDim.x >> 6) + (threadIdx.x >> 6);
    int wstep = gridDim.x * (blockDim.x >> 6);
    for (int w = wave0; w < W; w += wstep) {
        int tile = w >> 3, jb = w & 7, j0 = jb * 64;
        int tr = tile * 16 + r;
        int rA = (tr < cnt) ? order[start + tr] : NN;
        const u16* pa = ZB + (size_t)rA * 512 + q * 8;
        const u16* pbu[4];
#pragma unroll
        for (int jt = 0; jt < 4; ++jt)
            pbu[jt] = Wum + (size_t)(j0 + jt * 16 + r) * 512 + q * 8;
        f32x4 au[4] = {};
#pragma unroll 4
        for (int ko = 0; ko < 512; ko += 32) {
            bf16x8 a = *(const bf16x8*)(pa + ko);
#pragma unroll
            for (int jt = 0; jt < 4; ++jt)
                au[jt] = __builtin_amdgcn_mfma_f32_16x16x32_bf16(a, *(const bf16x8*)(pbu[jt] + ko), au[jt], 0, 0, 0);
        }
#pragma unroll
        for (int i2 = 0; i2 < 4; ++i2) {
            int ti = tile * 16 + q * 4 + i2;
            if (ti >= cnt) continue;
            int ni = order[start + ti];
            int p = parent[ni];
            size_t gb = (size_t)ni * 1536, nb = (size_t)ni * 512, pb = (size_t)p * 512;
            size_t qb = (size_t)ni * PXC;
#pragma unroll
            for (int jt = 0; jt < 4; ++jt) {
                int c = j0 + jt * 16 + r;
                float uu = tanhq(bfu(qx[qb + 2048 + c]) + au[jt][i2] + bfu(bum[c]));
                float ig = sigf(bfu(qx[qb + c]) + G[gb + c]);
                float og = sigf(bfu(qx[qb + 512 + c]) + G[gb + 512 + c]);
                float fg = sigf(bfu(qx[qb + 1024 + c]) + G[gb + 1024 + c]);
                float pc = Call[pb + c];
                float cc = ig * uu + fg * pc;
                float h = og * tanhq(cc);
                Call[nb + c] = cc;
                HB[nb + c] = f2bf(h);
            }
        }
    }
}

// ---------------- final max reduce ----------------
__global__ __launch_bounds__(256) void k_maxA(const u16* __restrict__ HB, float* __restrict__ pmax) {
    int b = blockIdx.x, t = threadIdx.x;
    float m1 = -1e30f, m2 = -1e30f;
    for (int rr = b * 128; rr < b * 128 + 128; ++rr) {
        m1 = fmaxf(m1, bfu(HB[(size_t)rr * 512 + t]));
        m2 = fmaxf(m2, bfu(HB[(size_t)rr * 512 + t + 256]));
    }
    pmax[(size_t)b * 512 + t] = m1; pmax[(size_t)b * 512 + t + 256] = m2;
}
__global__ void k_maxB(const float* __restrict__ pmax, void* __restrict__ outv,
                       const int* __restrict__ fcnt) {
    int j = threadIdx.x;
    float m = -1e30f;
    for (int b = 0; b < 64; ++b) m = fmaxf(m, pmax[(size_t)b * 512 + j]);
    bool isbf = (*fcnt > 2048);
    if (isbf) ((u16*)outv)[512 + j] = f2bf(m);
    else ((float*)outv)[512 + j] = m;
}

__global__ void k_wsfail(u16* out) {
    int i = blockIdx.x * 256 + threadIdx.x;
    if (i < 1024) out[i] = f2bf(12345.f);
}

// ---------------- launch ----------------
extern "C" void kernel_launch(void* const* d_in, const int* in_sizes, int n_in,
                              void* d_out, int out_size, void* d_ws, size_t ws_size,
                              hipStream_t stream) {
    char* base = (char*)d_ws;
    u16* px = (u16*)(base + OFF_PX);
    u16* qx = (u16*)(base + OFF_QX);
    float* acc_h = (float*)(base + OFF_ACCH);
    float* acc_fc = (float*)(base + OFF_ACCF);
    float* acc_zc = (float*)(base + OFF_ACCZ);
    float* Call = (float*)(base + OFF_C);
    u16* HB = (u16*)(base + OFF_HB);
    u16* ZB = (u16*)(base + OFF_ZB);
    float* G = (float*)(base + OFF_G);
    u16* NGI = (u16*)(base + OFF_G);       // normalized inputs overlay (pre-cs only)
    u16* NW = (u16*)(base + OFF_NW);
    int* depth = (int*)(base + OFF_DEPTH);
    int* order = (int*)(base + OFF_ORDER);
    int* counts = (int*)(base + OFF_MISC);
    int* cursor = counts + 64;
    int* fcnt = counts + 128;
    int* pcnt = counts + 129;
    int* lvl = (int*)(base + OFF_LVL);
    u16* NB = (u16*)(base + OFF_NB);
    int* pnorm = (int*)(base + OFF_PN);
    float* pmax = (float*)(base + OFF_PMAX);

    if (ws_size < WS_TOTAL) { k_wsfail<<<4, 256, 0, stream>>>((u16*)d_out); return; }

    hipMemsetAsync(base + OFF_MISC, 0, 1024, stream);
    hipMemsetAsync(base + OFF_ACCH, 0, 3 * SZ_ACC, stream);       // acc_h/fc/zc
    hipMemsetAsync(base + OFF_C, 0, SZ_ACC, stream);              // Ccs/Call
    hipMemsetAsync(base + OFF_HB, 0, 2 * SZ_HB, stream);          // HB + ZB
    hipMemsetAsync((char*)(px + (size_t)NN * PXC), 0, PXC * 2, stream);
    hipMemsetAsync((char*)(qx + (size_t)NN * PXC), 0, PXC * 2, stream);

    // dtype detect + normalize
    k_detect<<<16, 256, 0, stream>>>((const u32*)d_in[0], (const u32*)d_in[1], fcnt, pcnt);
    k_pnorm<<<32, 256, 0, stream>>>((const u32*)d_in[1], pcnt, pnorm);
    auto nf4 = [&](const void* s, u16* dst, int cnt_el) {
        int c4 = cnt_el >> 2;
        k_normf4<<<(c4 + 255) / 256, 256, 0, stream>>>(s, dst, c4, fcnt);
    };
    nf4(d_in[0],  NGI,            NN * 512);
    nf4(d_in[2],  NW + NW_CSWX,   2560 * 512);
    nf4(d_in[10], NW + NW_CHWX,   2560 * 512);
    nf4(d_in[4],  NW + NW_CSWIO,  1024 * 512);
    nf4(d_in[6],  NW + NW_CSWFZ,  1024 * 512);
    nf4(d_in[8],  NW + NW_CSWUM,  512 * 512);
    nf4(d_in[12], NW + NW_CHWH,   2048 * 512);
    nf4(d_in[14], NW + NW_CHWUM,  512 * 512);
    nf4(d_in[3],  NB + NB_CSBX,   2560);
    nf4(d_in[5],  NB + NB_CSBIO,  1024);
    nf4(d_in[7],  NB + NB_CSBFZ,  1024);
    nf4(d_in[9],  NB + NB_CSBUM,  512);
    nf4(d_in[11], NB + NB_CHBX,   2560);
    nf4(d_in[13], NB + NB_CHBH,   2048);
    nf4(d_in[15], NB + NB_CHBUM,  512);

    // level schedule
    k_depth<<<32, 256, 0, stream>>>(pnorm, depth);
    k_hist<<<32, 256, 0, stream>>>(depth, counts);
    k_scan<<<1, 64, 0, stream>>>(counts, lvl);
    k_scatter<<<32, 256, 0, stream>>>(depth, lvl, cursor, order);

    // input projections
    dim3 gg(PXC / 64, NN / 16);
    k_gemm_in<<<gg, 256, 0, stream>>>(NGI, NW + NW_CSWX, NB + NB_CSBX, px);
    k_gemm_in<<<gg, 256, 0, stream>>>(NGI, NW + NW_CHWX, NB + NB_CHBX, qx);

    // child-sum: deepest -> root
    for (int d = MAXD - 1; d >= 0; --d) {
        cs_lvl1<<<LVL_WG, 256, 0, stream>>>(order, lvl, d, pnorm,
                                            acc_h, acc_zc, acc_fc,
                                            NW + NW_CSWIO, NW + NW_CSWUM,
                                            NB + NB_CSBIO, NB + NB_CSBUM,
                                            px, Call, HB, d_out, fcnt);
        cs_lvl2<<<LVL_WG, 256, 0, stream>>>(order, lvl, d, pnorm,
                                            HB, Call, NW + NW_CSWFZ, NB + NB_CSBFZ,
                                            px, acc_fc, acc_zc);
    }

    // chain: root -> leaves (HB/Call rows are rewritten before any chain read;
    // sentinel row NN stayed zero through the cs pass)
    for (int d = 0; d < MAXD; ++d) {
        ch_lvl1<<<LVL_WG, 256, 0, stream>>>(order, lvl, d, pnorm,
                                            HB, Call, NW + NW_CHWH, NB + NB_CHBH,
                                            qx, G, ZB);
        ch_lvl2<<<LVL_WG, 256, 0, stream>>>(order, lvl, d, pnorm,
                                            ZB, qx, NW + NW_CHWUM, NB + NB_CHBUM,
                                            G, Call, HB);
    }

    // brep
    k_maxA<<<64, 256, 0, stream>>>(HB, pmax);
    k_maxB<<<1, 512, 0, stream>>>(pmax, d_out, fcnt);
}